// Round 1
// baseline (568.480 us; speedup 1.0000x reference)
//
#include <hip/hip_runtime.h>
#include <math.h>

#define N_NODES 50000
#define N_EDGES 800000
#define N_TOT   850000
#define IN_F    191
#define F1      256
#define NH1     16
#define NC1     16
#define F2      24
#define NH2     8
#define NC2     3

__device__ __forceinline__ float lrelu(float x) { return x > 0.f ? x : 0.2f * x; }

// ---------------- init: counts=1 (self loop), scalars=0 ----------------
__global__ void k_init(int* counts, float* scalars) {
    int i = blockIdx.x * blockDim.x + threadIdx.x;
    if (i < N_NODES) counts[i] = 1;
    if (i < 32) scalars[i] = 0.f;
}

// ---------------- sum of edge_attr ----------------
__global__ void k_easum(const float* __restrict__ ea, float* scalars) {
    int i = blockIdx.x * blockDim.x + threadIdx.x;
    float v = 0.f;
    for (int e = i; e < N_EDGES; e += gridDim.x * blockDim.x) v += ea[e];
    #pragma unroll
    for (int off = 32; off >= 1; off >>= 1) v += __shfl_xor(v, off);
    if ((threadIdx.x & 63) == 0) atomicAdd(&scalars[25], v);
}

// ---------------- we_dot per head + ea_mean ----------------
__global__ void k_wedot(const float* __restrict__ We1, const float* __restrict__ ae1,
                        const float* __restrict__ We2, const float* __restrict__ ae2,
                        float* scalars) {
    int t = threadIdx.x;
    if (t < NH1) {
        float s = 0.f;
        for (int c = 0; c < NC1; c++) s += We1[t * NC1 + c] * ae1[t * NC1 + c];
        scalars[1 + t] = s;
    } else if (t < NH1 + NH2) {
        int h = t - NH1;
        float s = 0.f;
        for (int c = 0; c < NC2; c++) s += We2[h * NC2 + c] * ae2[h * NC2 + c];
        scalars[17 + h] = s;
    } else if (t == 63) {
        scalars[0] = scalars[25] / (float)N_EDGES;   // ea_mean
    }
}

// ---------------- in-degree histogram ----------------
__global__ void k_hist(const int* __restrict__ ei, int* counts) {
    int e = blockIdx.x * blockDim.x + threadIdx.x;
    if (e < N_EDGES) atomicAdd(&counts[ei[N_EDGES + e]], 1);
}

// ---------------- exclusive scan (1 block, wave-scan based) ----------------
__global__ __launch_bounds__(1024) void k_scan(const int* __restrict__ counts,
                                               int* rowptr, int* cursor) {
    __shared__ int wsum[16];
    __shared__ int carry_s;
    int t = threadIdx.x;
    int lane = t & 63, w = t >> 6;
    if (t == 0) carry_s = 0;
    __syncthreads();
    for (int base = 0; base < N_NODES; base += 1024) {
        int i = base + t;
        int v = (i < N_NODES) ? counts[i] : 0;
        int incl = v;
        #pragma unroll
        for (int off = 1; off < 64; off <<= 1) {
            int u = __shfl_up(incl, off);
            if (lane >= off) incl += u;
        }
        if (lane == 63) wsum[w] = incl;
        __syncthreads();
        int woff = 0;
        for (int k = 0; k < w; k++) woff += wsum[k];
        int carry = carry_s;
        int excl = carry + woff + incl - v;
        if (i < N_NODES) { rowptr[i] = excl; cursor[i] = excl; }
        __syncthreads();
        if (t == 1023) carry_s = carry + woff + incl;
        __syncthreads();
    }
    if (t == 0) rowptr[N_NODES] = carry_s;
}

// ---------------- scatter edges (+self loops) into CSR ----------------
__global__ void k_scatter(const int* __restrict__ ei, const float* __restrict__ ea,
                          const float* __restrict__ scalars, int* cursor,
                          int* csr_src, float* csr_ea) {
    int i = blockIdx.x * blockDim.x + threadIdx.x;
    if (i < N_EDGES) {
        int s = ei[i], d = ei[N_EDGES + i];
        int pos = atomicAdd(&cursor[d], 1);
        csr_src[pos] = s;
        csr_ea[pos] = ea[i];
    } else if (i < N_TOT) {
        int n = i - N_EDGES;
        int pos = atomicAdd(&cursor[n], 1);
        csr_src[pos] = n;
        csr_ea[pos] = scalars[0];
    }
}

// ---------------- GEMM1: xl1 = x @ W1  (50000x191 @ 191x256) ----------------
#define BM 128
#define BK 32
__global__ __launch_bounds__(256) void k_gemm1(const float* __restrict__ x,
                                               const float* __restrict__ W1,
                                               float* __restrict__ xl1) {
    __shared__ float xs[BK][BM + 4];  // [k][m], row stride 132 floats (16B aligned)
    __shared__ float ws[BK][BM];      // [k][n]
    const int t = threadIdx.x;
    const int m0 = blockIdx.x * BM;
    const int n0 = blockIdx.y * BM;
    const int tx = t & 15, ty = t >> 4;
    float acc[8][8];
    #pragma unroll
    for (int i = 0; i < 8; i++)
        #pragma unroll
        for (int j = 0; j < 8; j++) acc[i][j] = 0.f;

    for (int kb = 0; kb < IN_F; kb += BK) {
        // stage x tile transposed
        {
            int j = t & 31;
            int mstart = t >> 5;
            int gk = kb + j;
            #pragma unroll
            for (int mm = mstart; mm < BM; mm += 8) {
                int gm = m0 + mm;
                float v = 0.f;
                if (gk < IN_F && gm < N_NODES) v = x[gm * IN_F + gk];
                xs[j][mm] = v;
            }
            int c = t & 127;
            int rstart = t >> 7;
            #pragma unroll
            for (int rr = rstart; rr < BK; rr += 2) {
                int gkw = kb + rr;
                ws[rr][c] = (gkw < IN_F) ? W1[gkw * F1 + n0 + c] : 0.f;
            }
        }
        __syncthreads();
        #pragma unroll
        for (int k = 0; k < BK; k++) {
            float4 a0 = *(const float4*)&xs[k][ty * 8];
            float4 a1 = *(const float4*)&xs[k][ty * 8 + 4];
            float4 b0 = *(const float4*)&ws[k][tx * 8];
            float4 b1 = *(const float4*)&ws[k][tx * 8 + 4];
            float a[8] = {a0.x, a0.y, a0.z, a0.w, a1.x, a1.y, a1.z, a1.w};
            float b[8] = {b0.x, b0.y, b0.z, b0.w, b1.x, b1.y, b1.z, b1.w};
            #pragma unroll
            for (int i = 0; i < 8; i++)
                #pragma unroll
                for (int j = 0; j < 8; j++) acc[i][j] += a[i] * b[j];
        }
        __syncthreads();
    }
    #pragma unroll
    for (int i = 0; i < 8; i++) {
        int gm = m0 + ty * 8 + i;
        if (gm < N_NODES) {
            *(float4*)&xl1[gm * F1 + n0 + tx * 8] =
                make_float4(acc[i][0], acc[i][1], acc[i][2], acc[i][3]);
            *(float4*)&xl1[gm * F1 + n0 + tx * 8 + 4] =
                make_float4(acc[i][4], acc[i][5], acc[i][6], acc[i][7]);
        }
    }
}

// ---------------- alpha_src1/alpha_dst1 ----------------
__global__ void k_alphas1(const float* __restrict__ xl1, const float* __restrict__ a_src,
                          const float* __restrict__ a_dst,
                          float* __restrict__ asrc, float* __restrict__ adst) {
    int idx = blockIdx.x * blockDim.x + threadIdx.x;   // n*16 + h
    if (idx >= N_NODES * NH1) return;
    int h = idx & 15;
    const float4* xp = (const float4*)(xl1 + (size_t)idx * 16);
    const float4* sp = (const float4*)(a_src + h * 16);
    const float4* dp = (const float4*)(a_dst + h * 16);
    float as = 0.f, ad = 0.f;
    #pragma unroll
    for (int r = 0; r < 4; r++) {
        float4 v = xp[r], s = sp[r], d = dp[r];
        as += v.x * s.x + v.y * s.y + v.z * s.z + v.w * s.w;
        ad += v.x * d.x + v.y * d.y + v.z * d.z + v.w * d.w;
    }
    asrc[idx] = as;
    adst[idx] = ad;
}

// ---------------- aggregation layer 1 (wave per node) ----------------
__global__ __launch_bounds__(256) void k_agg1(const int* __restrict__ rowptr,
        const int* __restrict__ csr_src, const float* __restrict__ csr_ea,
        const float* __restrict__ xl1, const float* __restrict__ asrc,
        const float* __restrict__ adst, const float* __restrict__ scalars,
        const float* __restrict__ b1, float* __restrict__ h1out) {
    int node = blockIdx.x * 4 + (threadIdx.x >> 6);
    int lane = threadIdx.x & 63;
    int eg = lane >> 4, h = lane & 15;
    int r0 = rowptr[node], r1 = rowptr[node + 1];
    float ad = adst[node * 16 + h];
    float wd = scalars[1 + h];
    float m = -1e30f;
    for (int j = r0 + eg; j < r1; j += 4) {
        int s = csr_src[j];
        float a = lrelu(asrc[s * 16 + h] + ad + csr_ea[j] * wd);
        m = fmaxf(m, a);
    }
    m = fmaxf(m, __shfl_xor(m, 16));
    m = fmaxf(m, __shfl_xor(m, 32));
    float den = 0.f;
    float acc[16];
    #pragma unroll
    for (int c = 0; c < 16; c++) acc[c] = 0.f;
    for (int j = r0 + eg; j < r1; j += 4) {
        int s = csr_src[j];
        float a = lrelu(asrc[s * 16 + h] + ad + csr_ea[j] * wd);
        float w = __expf(a - m);
        den += w;
        const float4* xp = (const float4*)(xl1 + (size_t)s * F1 + h * 16);
        float4 v0 = xp[0], v1 = xp[1], v2 = xp[2], v3 = xp[3];
        acc[0] += w * v0.x; acc[1] += w * v0.y; acc[2] += w * v0.z; acc[3] += w * v0.w;
        acc[4] += w * v1.x; acc[5] += w * v1.y; acc[6] += w * v1.z; acc[7] += w * v1.w;
        acc[8] += w * v2.x; acc[9] += w * v2.y; acc[10] += w * v2.z; acc[11] += w * v2.w;
        acc[12] += w * v3.x; acc[13] += w * v3.y; acc[14] += w * v3.z; acc[15] += w * v3.w;
    }
    den += __shfl_xor(den, 16);
    den += __shfl_xor(den, 32);
    float inv = 1.f / (den + 1e-16f);
    #pragma unroll
    for (int c = 0; c < 16; c++) {
        acc[c] += __shfl_xor(acc[c], 16);
        acc[c] += __shfl_xor(acc[c], 32);
    }
    if (eg == 0) {
        float o[16];
        #pragma unroll
        for (int c = 0; c < 16; c++) {
            float v = acc[c] * inv + b1[h * 16 + c];
            o[c] = v > 0.f ? v : expm1f(v);   // ELU
        }
        float4* op = (float4*)(h1out + (size_t)node * F1 + h * 16);
        op[0] = make_float4(o[0], o[1], o[2], o[3]);
        op[1] = make_float4(o[4], o[5], o[6], o[7]);
        op[2] = make_float4(o[8], o[9], o[10], o[11]);
        op[3] = make_float4(o[12], o[13], o[14], o[15]);
    }
}

// ---------------- GEMM2: xl2 = h1 @ W2  (50000x256 @ 256x24) ----------------
__global__ __launch_bounds__(256) void k_gemm2(const float* __restrict__ h1,
                                               const float* __restrict__ W2,
                                               float* __restrict__ xl2) {
    __shared__ float W2t[F2][268];   // transposed, padded row stride (1072B, 16B-aligned)
    int t = threadIdx.x;
    for (int i = t; i < 256 * F2; i += 256) {
        int k = i / F2, c = i - k * F2;
        W2t[c][k] = W2[i];
    }
    __syncthreads();
    int idx = blockIdx.x * 256 + t;
    if (idx >= N_NODES * F2) return;
    int n = idx / F2, col = idx - n * F2;
    const float4* hp = (const float4*)(h1 + (size_t)n * F1);
    const float4* wp = (const float4*)(&W2t[col][0]);
    float acc = 0.f;
    #pragma unroll 8
    for (int q = 0; q < 64; q++) {
        float4 hv = hp[q];
        float4 wv = wp[q];
        acc += hv.x * wv.x + hv.y * wv.y + hv.z * wv.z + hv.w * wv.w;
    }
    xl2[idx] = acc;
}

// ---------------- alpha_src2/alpha_dst2 ----------------
__global__ void k_alphas2(const float* __restrict__ xl2, const float* __restrict__ a_src,
                          const float* __restrict__ a_dst,
                          float* __restrict__ asrc, float* __restrict__ adst) {
    int idx = blockIdx.x * blockDim.x + threadIdx.x;   // n*8 + h
    if (idx >= N_NODES * NH2) return;
    int h = idx & 7;
    float x0 = xl2[idx * 3 + 0], x1 = xl2[idx * 3 + 1], x2 = xl2[idx * 3 + 2];
    asrc[idx] = x0 * a_src[h * 3 + 0] + x1 * a_src[h * 3 + 1] + x2 * a_src[h * 3 + 2];
    adst[idx] = x0 * a_dst[h * 3 + 0] + x1 * a_dst[h * 3 + 1] + x2 * a_dst[h * 3 + 2];
}

// ---------------- aggregation layer 2 (wave per node, mean over heads) ----------------
__global__ __launch_bounds__(256) void k_agg2(const int* __restrict__ rowptr,
        const int* __restrict__ csr_src, const float* __restrict__ csr_ea,
        const float* __restrict__ xl2, const float* __restrict__ asrc,
        const float* __restrict__ adst, const float* __restrict__ scalars,
        const float* __restrict__ b2, float* __restrict__ out) {
    int node = blockIdx.x * 4 + (threadIdx.x >> 6);
    int lane = threadIdx.x & 63;
    int eg = lane >> 3, h = lane & 7;
    int r0 = rowptr[node], r1 = rowptr[node + 1];
    float ad = adst[node * 8 + h];
    float wd = scalars[17 + h];
    float m = -1e30f;
    for (int j = r0 + eg; j < r1; j += 8) {
        int s = csr_src[j];
        float a = lrelu(asrc[s * 8 + h] + ad + csr_ea[j] * wd);
        m = fmaxf(m, a);
    }
    m = fmaxf(m, __shfl_xor(m, 8));
    m = fmaxf(m, __shfl_xor(m, 16));
    m = fmaxf(m, __shfl_xor(m, 32));
    float den = 0.f, a0 = 0.f, a1 = 0.f, a2 = 0.f;
    for (int j = r0 + eg; j < r1; j += 8) {
        int s = csr_src[j];
        float a = lrelu(asrc[s * 8 + h] + ad + csr_ea[j] * wd);
        float w = __expf(a - m);
        den += w;
        const float* xp = xl2 + (size_t)s * F2 + h * 3;
        a0 += w * xp[0];
        a1 += w * xp[1];
        a2 += w * xp[2];
    }
    den += __shfl_xor(den, 8); den += __shfl_xor(den, 16); den += __shfl_xor(den, 32);
    float inv = 1.f / (den + 1e-16f);
    a0 += __shfl_xor(a0, 8); a0 += __shfl_xor(a0, 16); a0 += __shfl_xor(a0, 32);
    a1 += __shfl_xor(a1, 8); a1 += __shfl_xor(a1, 16); a1 += __shfl_xor(a1, 32);
    a2 += __shfl_xor(a2, 8); a2 += __shfl_xor(a2, 16); a2 += __shfl_xor(a2, 32);
    a0 *= inv; a1 *= inv; a2 *= inv;
    // mean over heads (bits 0..2 of lane)
    a0 += __shfl_xor(a0, 1); a0 += __shfl_xor(a0, 2); a0 += __shfl_xor(a0, 4);
    a1 += __shfl_xor(a1, 1); a1 += __shfl_xor(a1, 2); a1 += __shfl_xor(a1, 4);
    a2 += __shfl_xor(a2, 1); a2 += __shfl_xor(a2, 2); a2 += __shfl_xor(a2, 4);
    if (lane == 0) {
        float v0 = a0 * 0.125f + b2[0];
        float v1 = a1 * 0.125f + b2[1];
        float v2 = a2 * 0.125f + b2[2];
        out[node * 3 + 0] = v0 > 0.f ? v0 : expm1f(v0);
        out[node * 3 + 1] = v1 > 0.f ? v1 : expm1f(v1);
        out[node * 3 + 2] = v2 > 0.f ? v2 : expm1f(v2);
    }
}

extern "C" void kernel_launch(void* const* d_in, const int* in_sizes, int n_in,
                              void* d_out, int out_size, void* d_ws, size_t ws_size,
                              hipStream_t stream) {
    const float* x       = (const float*)d_in[0];
    const int*   ei      = (const int*)d_in[1];
    const float* ea      = (const float*)d_in[2];
    const float* W1      = (const float*)d_in[3];
    const float* We1     = (const float*)d_in[4];
    const float* a_src1  = (const float*)d_in[5];
    const float* a_dst1  = (const float*)d_in[6];
    const float* a_edge1 = (const float*)d_in[7];
    const float* b1      = (const float*)d_in[8];
    const float* W2      = (const float*)d_in[9];
    const float* We2     = (const float*)d_in[10];
    const float* a_src2  = (const float*)d_in[11];
    const float* a_dst2  = (const float*)d_in[12];
    const float* a_edge2 = (const float*)d_in[13];
    const float* b2      = (const float*)d_in[14];
    float* out = (float*)d_out;

    char* ws = (char*)d_ws;
    size_t off = 0;
    auto alloc = [&](size_t nbytes) -> void* {
        void* p = ws + off;
        off = (off + nbytes + 255) & ~(size_t)255;
        return p;
    };
    float* xl1     = (float*)alloc((size_t)N_NODES * F1 * 4);
    float* h1      = (float*)alloc((size_t)N_NODES * F1 * 4);
    float* asrc1   = (float*)alloc((size_t)N_NODES * NH1 * 4);
    float* adst1   = (float*)alloc((size_t)N_NODES * NH1 * 4);
    float* xl2     = (float*)alloc((size_t)N_NODES * F2 * 4);
    float* asrc2   = (float*)alloc((size_t)N_NODES * NH2 * 4);
    float* adst2   = (float*)alloc((size_t)N_NODES * NH2 * 4);
    int*   counts  = (int*)alloc((size_t)N_NODES * 4);
    int*   rowptr  = (int*)alloc((size_t)(N_NODES + 1) * 4);
    int*   cursor  = (int*)alloc((size_t)N_NODES * 4);
    int*   csr_src = (int*)alloc((size_t)N_TOT * 4);
    float* csr_ea  = (float*)alloc((size_t)N_TOT * 4);
    float* scalars = (float*)alloc(128);

    hipLaunchKernelGGL(k_init, dim3((N_NODES + 255) / 256), dim3(256), 0, stream,
                       counts, scalars);
    hipLaunchKernelGGL(k_easum, dim3(256), dim3(256), 0, stream, ea, scalars);
    hipLaunchKernelGGL(k_wedot, dim3(1), dim3(64), 0, stream,
                       We1, a_edge1, We2, a_edge2, scalars);
    hipLaunchKernelGGL(k_hist, dim3((N_EDGES + 255) / 256), dim3(256), 0, stream,
                       ei, counts);
    hipLaunchKernelGGL(k_scan, dim3(1), dim3(1024), 0, stream, counts, rowptr, cursor);
    hipLaunchKernelGGL(k_scatter, dim3((N_TOT + 255) / 256), dim3(256), 0, stream,
                       ei, ea, scalars, cursor, csr_src, csr_ea);
    hipLaunchKernelGGL(k_gemm1, dim3((N_NODES + BM - 1) / BM, F1 / BM), dim3(256), 0, stream,
                       x, W1, xl1);
    hipLaunchKernelGGL(k_alphas1, dim3((N_NODES * NH1 + 255) / 256), dim3(256), 0, stream,
                       xl1, a_src1, a_dst1, asrc1, adst1);
    hipLaunchKernelGGL(k_agg1, dim3(N_NODES / 4), dim3(256), 0, stream,
                       rowptr, csr_src, csr_ea, xl1, asrc1, adst1, scalars, b1, h1);
    hipLaunchKernelGGL(k_gemm2, dim3((N_NODES * F2 + 255) / 256), dim3(256), 0, stream,
                       h1, W2, xl2);
    hipLaunchKernelGGL(k_alphas2, dim3((N_NODES * NH2 + 255) / 256), dim3(256), 0, stream,
                       xl2, a_src2, a_dst2, asrc2, adst2);
    hipLaunchKernelGGL(k_agg2, dim3(N_NODES / 4), dim3(256), 0, stream,
                       rowptr, csr_src, csr_ea, xl2, asrc2, adst2, scalars, b2, out);
}

// Round 2
// 471.093 us; speedup vs baseline: 1.2067x; 1.2067x over previous
//
#include <hip/hip_runtime.h>
#include <math.h>
#include <stdint.h>

#define N_NODES 50000
#define N_EDGES 800000
#define N_TOT   850000
#define IN_F    191
#define F1      256
#define NH1     16
#define NC1     16
#define F2      24
#define NH2     8
#define NC2     3
#define KP      224          // K padded to 7*32
#define MPAD    50048        // 391*128

typedef __attribute__((ext_vector_type(8))) short bf16x8;
typedef __attribute__((ext_vector_type(4))) float f32x4;

#define GLL16(g, s) __builtin_amdgcn_global_load_lds( \
    (const __attribute__((address_space(1))) void*)(g), \
    (__attribute__((address_space(3))) void*)(s), 16, 0, 0)

__device__ __forceinline__ float lrelu(float x) { return x > 0.f ? x : 0.2f * x; }

// round-to-nearest-even fp32 -> bf16, also return the bf16 value as fp32
__device__ __forceinline__ uint16_t f2bf(float f, float* back) {
    uint32_t u = __float_as_uint(f);
    uint32_t r = (u + 0x7fffu + ((u >> 16) & 1u)) >> 16;
    *back = __uint_as_float(r << 16);
    return (uint16_t)r;
}

// ---------------- init: counts=1 (self loop), scalars=0 ----------------
__global__ void k_init(int* counts, float* scalars) {
    int i = blockIdx.x * blockDim.x + threadIdx.x;
    if (i < N_NODES) counts[i] = 1;
    if (i < 32) scalars[i] = 0.f;
}

// ---------------- sum of edge_attr ----------------
__global__ void k_easum(const float* __restrict__ ea, float* scalars) {
    int i = blockIdx.x * blockDim.x + threadIdx.x;
    float v = 0.f;
    for (int e = i; e < N_EDGES; e += gridDim.x * blockDim.x) v += ea[e];
    #pragma unroll
    for (int off = 32; off >= 1; off >>= 1) v += __shfl_xor(v, off);
    if ((threadIdx.x & 63) == 0) atomicAdd(&scalars[25], v);
}

// ---------------- we_dot per head + ea_mean ----------------
__global__ void k_wedot(const float* __restrict__ We1, const float* __restrict__ ae1,
                        const float* __restrict__ We2, const float* __restrict__ ae2,
                        float* scalars) {
    int t = threadIdx.x;
    if (t < NH1) {
        float s = 0.f;
        for (int c = 0; c < NC1; c++) s += We1[t * NC1 + c] * ae1[t * NC1 + c];
        scalars[1 + t] = s;
    } else if (t < NH1 + NH2) {
        int h = t - NH1;
        float s = 0.f;
        for (int c = 0; c < NC2; c++) s += We2[h * NC2 + c] * ae2[h * NC2 + c];
        scalars[17 + h] = s;
    } else if (t == 63) {
        scalars[0] = scalars[25] / (float)N_EDGES;   // ea_mean
    }
}

// ---------------- in-degree histogram ----------------
__global__ void k_hist(const int* __restrict__ ei, int* counts) {
    int e = blockIdx.x * blockDim.x + threadIdx.x;
    if (e < N_EDGES) atomicAdd(&counts[ei[N_EDGES + e]], 1);
}

// ---------------- exclusive scan (1 block, wave-scan based) ----------------
__global__ __launch_bounds__(1024) void k_scan(const int* __restrict__ counts,
                                               int* rowptr, int* cursor) {
    __shared__ int wsum[16];
    __shared__ int carry_s;
    int t = threadIdx.x;
    int lane = t & 63, w = t >> 6;
    if (t == 0) carry_s = 0;
    __syncthreads();
    for (int base = 0; base < N_NODES; base += 1024) {
        int i = base + t;
        int v = (i < N_NODES) ? counts[i] : 0;
        int incl = v;
        #pragma unroll
        for (int off = 1; off < 64; off <<= 1) {
            int u = __shfl_up(incl, off);
            if (lane >= off) incl += u;
        }
        if (lane == 63) wsum[w] = incl;
        __syncthreads();
        int woff = 0;
        for (int k = 0; k < w; k++) woff += wsum[k];
        int carry = carry_s;
        int excl = carry + woff + incl - v;
        if (i < N_NODES) { rowptr[i] = excl; cursor[i] = excl; }
        __syncthreads();
        if (t == 1023) carry_s = carry + woff + incl;
        __syncthreads();
    }
    if (t == 0) rowptr[N_NODES] = carry_s;
}

// ---------------- scatter edges (+self loops) into CSR ----------------
__global__ void k_scatter(const int* __restrict__ ei, const float* __restrict__ ea,
                          const float* __restrict__ scalars, int* cursor,
                          int* csr_src, float* csr_ea) {
    int i = blockIdx.x * blockDim.x + threadIdx.x;
    if (i < N_EDGES) {
        int s = ei[i], d = ei[N_EDGES + i];
        int pos = atomicAdd(&cursor[d], 1);
        csr_src[pos] = s;
        csr_ea[pos] = ea[i];
    } else if (i < N_TOT) {
        int n = i - N_EDGES;
        int pos = atomicAdd(&cursor[n], 1);
        csr_src[pos] = n;
        csr_ea[pos] = scalars[0];
    }
}

// ---------------- convert x -> (xh, xl) bf16 split, padded [MPAD][KP] ----------------
__global__ void k_cvt_x(const float* __restrict__ x, uint16_t* __restrict__ xh,
                        uint16_t* __restrict__ xl) {
    int idx = blockIdx.x * 256 + threadIdx.x;     // row*28 + kw
    if (idx >= MPAD * 28) return;
    int row = idx / 28, kw = idx - row * 28;
    int k0 = kw * 8;
    uint16_t hv[8], lv[8];
    #pragma unroll
    for (int j = 0; j < 8; j++) {
        int k = k0 + j;
        float v = (row < N_NODES && k < IN_F) ? x[(size_t)row * IN_F + k] : 0.f;
        float hf;
        hv[j] = f2bf(v, &hf);
        float lo = v - hf;
        float lf;
        lv[j] = f2bf(lo, &lf);
    }
    *(uint4*)(xh + (size_t)row * KP + k0) = *(const uint4*)hv;
    *(uint4*)(xl + (size_t)row * KP + k0) = *(const uint4*)lv;
}

// ---------------- convert W1 -> (WhT, WlT) bf16 split transposed [F1][KP] ----------------
__global__ void k_cvt_w(const float* __restrict__ W1, uint16_t* __restrict__ wht,
                        uint16_t* __restrict__ wlt) {
    int idx = blockIdx.x * 256 + threadIdx.x;     // col*28 + kw
    if (idx >= F1 * 28) return;
    int col = idx / 28, kw = idx - col * 28;
    int k0 = kw * 8;
    uint16_t hv[8], lv[8];
    #pragma unroll
    for (int j = 0; j < 8; j++) {
        int k = k0 + j;
        float v = (k < IN_F) ? W1[(size_t)k * F1 + col] : 0.f;
        float hf;
        hv[j] = f2bf(v, &hf);
        float lo = v - hf;
        float lf;
        lv[j] = f2bf(lo, &lf);
    }
    *(uint4*)(wht + (size_t)col * KP + k0) = *(const uint4*)hv;
    *(uint4*)(wlt + (size_t)col * KP + k0) = *(const uint4*)lv;
}

// ---------------- GEMM1 via MFMA: xl1 = x @ W1, bf16 hi/lo split (3 terms) ----------------
// 128x128 tile per block, 4 waves (2x2), each wave 64x64 = 4x4 frags of 16x16x32.
// LDS fragment-ordered [frag][lane][8bf16]; staged with global_load_lds (16B).
__global__ __launch_bounds__(256) void k_gemm1_mfma(const uint16_t* __restrict__ xh,
        const uint16_t* __restrict__ xl, const uint16_t* __restrict__ wht,
        const uint16_t* __restrict__ wlt, float* __restrict__ xl1) {
    __shared__ uint16_t lds[4 * 8 * 64 * 8];   // Ah, Al, Bh, Bl ; 32 KiB
    const int t = threadIdx.x;
    const int l = t & 63, w = t >> 6;
    const int wm = w >> 1, wn = w & 1;
    const int m0 = blockIdx.x * 128;
    const int n0 = blockIdx.y * 128;
    const int lr = l & 15, lk = l >> 4;

    uint16_t* ldsAh = lds;
    uint16_t* ldsAl = lds + 8 * 64 * 8;
    uint16_t* ldsBh = lds + 2 * 8 * 64 * 8;
    uint16_t* ldsBl = lds + 3 * 8 * 64 * 8;

    f32x4 acc[4][4];
    #pragma unroll
    for (int i = 0; i < 4; i++)
        #pragma unroll
        for (int j = 0; j < 4; j++)
            acc[i][j] = (f32x4){0.f, 0.f, 0.f, 0.f};

    for (int ks = 0; ks < 7; ks++) {
        const int kb = ks * 32 + lk * 8;
        #pragma unroll
        for (int ii = 0; ii < 2; ii++) {
            const int f = 2 * w + ii;
            const uint16_t* sAh = xh  + (size_t)(m0 + f * 16 + lr) * KP + kb;
            const uint16_t* sAl = xl  + (size_t)(m0 + f * 16 + lr) * KP + kb;
            const uint16_t* sBh = wht + (size_t)(n0 + f * 16 + lr) * KP + kb;
            const uint16_t* sBl = wlt + (size_t)(n0 + f * 16 + lr) * KP + kb;
            GLL16(sAh, ldsAh + f * 512);
            GLL16(sAl, ldsAl + f * 512);
            GLL16(sBh, ldsBh + f * 512);
            GLL16(sBl, ldsBl + f * 512);
        }
        __syncthreads();
        bf16x8 ah[4], al[4];
        #pragma unroll
        for (int i = 0; i < 4; i++) {
            const int f = wm * 4 + i;
            ah[i] = *(const bf16x8*)(ldsAh + (f * 64 + l) * 8);
            al[i] = *(const bf16x8*)(ldsAl + (f * 64 + l) * 8);
        }
        #pragma unroll
        for (int j = 0; j < 4; j++) {
            const int g = wn * 4 + j;
            bf16x8 bh = *(const bf16x8*)(ldsBh + (g * 64 + l) * 8);
            bf16x8 bl = *(const bf16x8*)(ldsBl + (g * 64 + l) * 8);
            #pragma unroll
            for (int i = 0; i < 4; i++) {
                acc[i][j] = __builtin_amdgcn_mfma_f32_16x16x32_bf16(ah[i], bh, acc[i][j], 0, 0, 0);
                acc[i][j] = __builtin_amdgcn_mfma_f32_16x16x32_bf16(ah[i], bl, acc[i][j], 0, 0, 0);
                acc[i][j] = __builtin_amdgcn_mfma_f32_16x16x32_bf16(al[i], bh, acc[i][j], 0, 0, 0);
            }
        }
        __syncthreads();
    }
    // C write: row = (lane>>4)*4 + r, col = lane&15 within each 16x16 frag
    #pragma unroll
    for (int i = 0; i < 4; i++) {
        const int gm_base = m0 + wm * 64 + i * 16 + lk * 4;
        #pragma unroll
        for (int r = 0; r < 4; r++) {
            const int gm = gm_base + r;
            if (gm < N_NODES) {
                #pragma unroll
                for (int j = 0; j < 4; j++) {
                    const int gn = n0 + wn * 64 + j * 16 + lr;
                    xl1[(size_t)gm * F1 + gn] = acc[i][j][r];
                }
            }
        }
    }
}

// ---------------- alpha_src1/alpha_dst1 ----------------
__global__ void k_alphas1(const float* __restrict__ xl1, const float* __restrict__ a_src,
                          const float* __restrict__ a_dst,
                          float* __restrict__ asrc, float* __restrict__ adst) {
    int idx = blockIdx.x * blockDim.x + threadIdx.x;   // n*16 + h
    if (idx >= N_NODES * NH1) return;
    int h = idx & 15;
    const float4* xp = (const float4*)(xl1 + (size_t)idx * 16);
    const float4* sp = (const float4*)(a_src + h * 16);
    const float4* dp = (const float4*)(a_dst + h * 16);
    float as = 0.f, ad = 0.f;
    #pragma unroll
    for (int r = 0; r < 4; r++) {
        float4 v = xp[r], s = sp[r], d = dp[r];
        as += v.x * s.x + v.y * s.y + v.z * s.z + v.w * s.w;
        ad += v.x * d.x + v.y * d.y + v.z * d.z + v.w * d.w;
    }
    asrc[idx] = as;
    adst[idx] = ad;
}

// ---------------- aggregation layer 1 (wave per node) ----------------
__global__ __launch_bounds__(256) void k_agg1(const int* __restrict__ rowptr,
        const int* __restrict__ csr_src, const float* __restrict__ csr_ea,
        const float* __restrict__ xl1, const float* __restrict__ asrc,
        const float* __restrict__ adst, const float* __restrict__ scalars,
        const float* __restrict__ b1, float* __restrict__ h1out) {
    int node = blockIdx.x * 4 + (threadIdx.x >> 6);
    int lane = threadIdx.x & 63;
    int eg = lane >> 4, h = lane & 15;
    int r0 = rowptr[node], r1 = rowptr[node + 1];
    float ad = adst[node * 16 + h];
    float wd = scalars[1 + h];
    float m = -1e30f;
    for (int j = r0 + eg; j < r1; j += 4) {
        int s = csr_src[j];
        float a = lrelu(asrc[s * 16 + h] + ad + csr_ea[j] * wd);
        m = fmaxf(m, a);
    }
    m = fmaxf(m, __shfl_xor(m, 16));
    m = fmaxf(m, __shfl_xor(m, 32));
    float den = 0.f;
    float acc[16];
    #pragma unroll
    for (int c = 0; c < 16; c++) acc[c] = 0.f;
    for (int j = r0 + eg; j < r1; j += 4) {
        int s = csr_src[j];
        float a = lrelu(asrc[s * 16 + h] + ad + csr_ea[j] * wd);
        float wgt = __expf(a - m);
        den += wgt;
        const float4* xp = (const float4*)(xl1 + (size_t)s * F1 + h * 16);
        float4 v0 = xp[0], v1 = xp[1], v2 = xp[2], v3 = xp[3];
        acc[0] += wgt * v0.x; acc[1] += wgt * v0.y; acc[2] += wgt * v0.z; acc[3] += wgt * v0.w;
        acc[4] += wgt * v1.x; acc[5] += wgt * v1.y; acc[6] += wgt * v1.z; acc[7] += wgt * v1.w;
        acc[8] += wgt * v2.x; acc[9] += wgt * v2.y; acc[10] += wgt * v2.z; acc[11] += wgt * v2.w;
        acc[12] += wgt * v3.x; acc[13] += wgt * v3.y; acc[14] += wgt * v3.z; acc[15] += wgt * v3.w;
    }
    den += __shfl_xor(den, 16);
    den += __shfl_xor(den, 32);
    float inv = 1.f / (den + 1e-16f);
    #pragma unroll
    for (int c = 0; c < 16; c++) {
        acc[c] += __shfl_xor(acc[c], 16);
        acc[c] += __shfl_xor(acc[c], 32);
    }
    if (eg == 0) {
        float o[16];
        #pragma unroll
        for (int c = 0; c < 16; c++) {
            float v = acc[c] * inv + b1[h * 16 + c];
            o[c] = v > 0.f ? v : expm1f(v);   // ELU
        }
        float4* op = (float4*)(h1out + (size_t)node * F1 + h * 16);
        op[0] = make_float4(o[0], o[1], o[2], o[3]);
        op[1] = make_float4(o[4], o[5], o[6], o[7]);
        op[2] = make_float4(o[8], o[9], o[10], o[11]);
        op[3] = make_float4(o[12], o[13], o[14], o[15]);
    }
}

// ---------------- GEMM2: xl2 = h1 @ W2  (50000x256 @ 256x24) ----------------
__global__ __launch_bounds__(256) void k_gemm2(const float* __restrict__ h1,
                                               const float* __restrict__ W2,
                                               float* __restrict__ xl2) {
    __shared__ float W2t[F2][268];
    int t = threadIdx.x;
    for (int i = t; i < 256 * F2; i += 256) {
        int k = i / F2, c = i - k * F2;
        W2t[c][k] = W2[i];
    }
    __syncthreads();
    int idx = blockIdx.x * 256 + t;
    if (idx >= N_NODES * F2) return;
    int n = idx / F2, col = idx - n * F2;
    const float4* hp = (const float4*)(h1 + (size_t)n * F1);
    const float4* wp = (const float4*)(&W2t[col][0]);
    float acc = 0.f;
    #pragma unroll 8
    for (int q = 0; q < 64; q++) {
        float4 hv = hp[q];
        float4 wv = wp[q];
        acc += hv.x * wv.x + hv.y * wv.y + hv.z * wv.z + hv.w * wv.w;
    }
    xl2[idx] = acc;
}

// ---------------- alpha_src2/alpha_dst2 ----------------
__global__ void k_alphas2(const float* __restrict__ xl2, const float* __restrict__ a_src,
                          const float* __restrict__ a_dst,
                          float* __restrict__ asrc, float* __restrict__ adst) {
    int idx = blockIdx.x * blockDim.x + threadIdx.x;   // n*8 + h
    if (idx >= N_NODES * NH2) return;
    int h = idx & 7;
    float x0 = xl2[idx * 3 + 0], x1 = xl2[idx * 3 + 1], x2 = xl2[idx * 3 + 2];
    asrc[idx] = x0 * a_src[h * 3 + 0] + x1 * a_src[h * 3 + 1] + x2 * a_src[h * 3 + 2];
    adst[idx] = x0 * a_dst[h * 3 + 0] + x1 * a_dst[h * 3 + 1] + x2 * a_dst[h * 3 + 2];
}

// ---------------- aggregation layer 2 (wave per node, mean over heads) ----------------
__global__ __launch_bounds__(256) void k_agg2(const int* __restrict__ rowptr,
        const int* __restrict__ csr_src, const float* __restrict__ csr_ea,
        const float* __restrict__ xl2, const float* __restrict__ asrc,
        const float* __restrict__ adst, const float* __restrict__ scalars,
        const float* __restrict__ b2, float* __restrict__ out) {
    int node = blockIdx.x * 4 + (threadIdx.x >> 6);
    int lane = threadIdx.x & 63;
    int eg = lane >> 3, h = lane & 7;
    int r0 = rowptr[node], r1 = rowptr[node + 1];
    float ad = adst[node * 8 + h];
    float wd = scalars[17 + h];
    float m = -1e30f;
    for (int j = r0 + eg; j < r1; j += 8) {
        int s = csr_src[j];
        float a = lrelu(asrc[s * 8 + h] + ad + csr_ea[j] * wd);
        m = fmaxf(m, a);
    }
    m = fmaxf(m, __shfl_xor(m, 8));
    m = fmaxf(m, __shfl_xor(m, 16));
    m = fmaxf(m, __shfl_xor(m, 32));
    float den = 0.f, a0 = 0.f, a1 = 0.f, a2 = 0.f;
    for (int j = r0 + eg; j < r1; j += 8) {
        int s = csr_src[j];
        float a = lrelu(asrc[s * 8 + h] + ad + csr_ea[j] * wd);
        float wgt = __expf(a - m);
        den += wgt;
        const float* xp = xl2 + (size_t)s * F2 + h * 3;
        a0 += wgt * xp[0];
        a1 += wgt * xp[1];
        a2 += wgt * xp[2];
    }
    den += __shfl_xor(den, 8); den += __shfl_xor(den, 16); den += __shfl_xor(den, 32);
    float inv = 1.f / (den + 1e-16f);
    a0 += __shfl_xor(a0, 8); a0 += __shfl_xor(a0, 16); a0 += __shfl_xor(a0, 32);
    a1 += __shfl_xor(a1, 8); a1 += __shfl_xor(a1, 16); a1 += __shfl_xor(a1, 32);
    a2 += __shfl_xor(a2, 8); a2 += __shfl_xor(a2, 16); a2 += __shfl_xor(a2, 32);
    a0 *= inv; a1 *= inv; a2 *= inv;
    a0 += __shfl_xor(a0, 1); a0 += __shfl_xor(a0, 2); a0 += __shfl_xor(a0, 4);
    a1 += __shfl_xor(a1, 1); a1 += __shfl_xor(a1, 2); a1 += __shfl_xor(a1, 4);
    a2 += __shfl_xor(a2, 1); a2 += __shfl_xor(a2, 2); a2 += __shfl_xor(a2, 4);
    if (lane == 0) {
        float v0 = a0 * 0.125f + b2[0];
        float v1 = a1 * 0.125f + b2[1];
        float v2 = a2 * 0.125f + b2[2];
        out[node * 3 + 0] = v0 > 0.f ? v0 : expm1f(v0);
        out[node * 3 + 1] = v1 > 0.f ? v1 : expm1f(v1);
        out[node * 3 + 2] = v2 > 0.f ? v2 : expm1f(v2);
    }
}

extern "C" void kernel_launch(void* const* d_in, const int* in_sizes, int n_in,
                              void* d_out, int out_size, void* d_ws, size_t ws_size,
                              hipStream_t stream) {
    const float* x       = (const float*)d_in[0];
    const int*   ei      = (const int*)d_in[1];
    const float* ea      = (const float*)d_in[2];
    const float* W1      = (const float*)d_in[3];
    const float* We1     = (const float*)d_in[4];
    const float* a_src1  = (const float*)d_in[5];
    const float* a_dst1  = (const float*)d_in[6];
    const float* a_edge1 = (const float*)d_in[7];
    const float* b1      = (const float*)d_in[8];
    const float* W2      = (const float*)d_in[9];
    const float* We2     = (const float*)d_in[10];
    const float* a_src2  = (const float*)d_in[11];
    const float* a_dst2  = (const float*)d_in[12];
    const float* a_edge2 = (const float*)d_in[13];
    const float* b2      = (const float*)d_in[14];
    float* out = (float*)d_out;

    char* ws = (char*)d_ws;
    size_t off = 0;
    auto alloc = [&](size_t nbytes) -> void* {
        void* p = ws + off;
        off = (off + nbytes + 255) & ~(size_t)255;
        return p;
    };
    float* xl1     = (float*)alloc((size_t)N_NODES * F1 * 4);
    float* h1      = (float*)alloc((size_t)N_NODES * F1 * 4);
    float* asrc1   = (float*)alloc((size_t)N_NODES * NH1 * 4);
    float* adst1   = (float*)alloc((size_t)N_NODES * NH1 * 4);
    float* xl2     = (float*)alloc((size_t)N_NODES * F2 * 4);
    float* asrc2   = (float*)alloc((size_t)N_NODES * NH2 * 4);
    float* adst2   = (float*)alloc((size_t)N_NODES * NH2 * 4);
    int*   counts  = (int*)alloc((size_t)N_NODES * 4);
    int*   rowptr  = (int*)alloc((size_t)(N_NODES + 1) * 4);
    int*   cursor  = (int*)alloc((size_t)N_NODES * 4);
    int*   csr_src = (int*)alloc((size_t)N_TOT * 4);
    float* csr_ea  = (float*)alloc((size_t)N_TOT * 4);
    float* scalars = (float*)alloc(128);
    uint16_t* wht  = (uint16_t*)alloc((size_t)F1 * KP * 2);
    uint16_t* wlt  = (uint16_t*)alloc((size_t)F1 * KP * 2);
    // xh/xl alias h1's buffer: consumed by gemm1 BEFORE agg1 writes h1 (stream-serial)
    uint16_t* xh = (uint16_t*)h1;
    uint16_t* xlo = xh + (size_t)MPAD * KP;   // 22.4MB + 22.4MB < 51.2MB

    hipLaunchKernelGGL(k_init, dim3((N_NODES + 255) / 256), dim3(256), 0, stream,
                       counts, scalars);
    hipLaunchKernelGGL(k_easum, dim3(256), dim3(256), 0, stream, ea, scalars);
    hipLaunchKernelGGL(k_wedot, dim3(1), dim3(64), 0, stream,
                       We1, a_edge1, We2, a_edge2, scalars);
    hipLaunchKernelGGL(k_hist, dim3((N_EDGES + 255) / 256), dim3(256), 0, stream,
                       ei, counts);
    hipLaunchKernelGGL(k_scan, dim3(1), dim3(1024), 0, stream, counts, rowptr, cursor);
    hipLaunchKernelGGL(k_scatter, dim3((N_TOT + 255) / 256), dim3(256), 0, stream,
                       ei, ea, scalars, cursor, csr_src, csr_ea);
    hipLaunchKernelGGL(k_cvt_x, dim3((MPAD * 28 + 255) / 256), dim3(256), 0, stream,
                       x, xh, xlo);
    hipLaunchKernelGGL(k_cvt_w, dim3((F1 * 28 + 255) / 256), dim3(256), 0, stream,
                       W1, wht, wlt);
    hipLaunchKernelGGL(k_gemm1_mfma, dim3(MPAD / 128, 2), dim3(256), 0, stream,
                       xh, xlo, wht, wlt, xl1);
    hipLaunchKernelGGL(k_alphas1, dim3((N_NODES * NH1 + 255) / 256), dim3(256), 0, stream,
                       xl1, a_src1, a_dst1, asrc1, adst1);
    hipLaunchKernelGGL(k_agg1, dim3(N_NODES / 4), dim3(256), 0, stream,
                       rowptr, csr_src, csr_ea, xl1, asrc1, adst1, scalars, b1, h1);
    hipLaunchKernelGGL(k_gemm2, dim3((N_NODES * F2 + 255) / 256), dim3(256), 0, stream,
                       h1, W2, xl2);
    hipLaunchKernelGGL(k_alphas2, dim3((N_NODES * NH2 + 255) / 256), dim3(256), 0, stream,
                       xl2, a_src2, a_dst2, asrc2, adst2);
    hipLaunchKernelGGL(k_agg2, dim3(N_NODES / 4), dim3(256), 0, stream,
                       rowptr, csr_src, csr_ea, xl2, asrc2, adst2, scalars, b2, out);
}

// Round 3
// 390.766 us; speedup vs baseline: 1.4548x; 1.2056x over previous
//
#include <hip/hip_runtime.h>
#include <math.h>
#include <stdint.h>

#define N_NODES 50000
#define N_EDGES 800000
#define N_TOT   850000
#define IN_F    191
#define F1      256
#define NH1     16
#define NC1     16
#define F2      24
#define NH2     8
#define NC2     3
#define KP      224          // K padded to 7*32
#define MPAD    50048        // 391*128

typedef __attribute__((ext_vector_type(8))) short bf16x8;
typedef __attribute__((ext_vector_type(4))) float f32x4;

#define GLL16(g, s) __builtin_amdgcn_global_load_lds( \
    (const __attribute__((address_space(1))) void*)(g), \
    (__attribute__((address_space(3))) void*)(s), 16, 0, 0)

__device__ __forceinline__ float lrelu(float x) { return x > 0.f ? x : 0.2f * x; }

// round-to-nearest-even fp32 -> bf16 (as u16)
__device__ __forceinline__ uint16_t f2bf1(float f) {
    uint32_t u = __float_as_uint(f);
    return (uint16_t)((u + 0x7fffu + ((u >> 16) & 1u)) >> 16);
}
// fp32 -> bf16, also return the rounded-back fp32
__device__ __forceinline__ uint16_t f2bf(float f, float* back) {
    uint32_t u = __float_as_uint(f);
    uint32_t r = (u + 0x7fffu + ((u >> 16) & 1u)) >> 16;
    *back = __uint_as_float(r << 16);
    return (uint16_t)r;
}
__device__ __forceinline__ void bf2f2(uint32_t u, float* lo, float* hi) {
    *lo = __uint_as_float(u << 16);
    *hi = __uint_as_float(u & 0xffff0000u);
}

// ---------------- init: counts=1 (self loop), scalars=0 ----------------
__global__ void k_init(int* counts, float* scalars) {
    int i = blockIdx.x * blockDim.x + threadIdx.x;
    if (i < N_NODES) counts[i] = 1;
    if (i < 32) scalars[i] = 0.f;
}

// ---------------- sum of edge_attr ----------------
__global__ void k_easum(const float* __restrict__ ea, float* scalars) {
    int i = blockIdx.x * blockDim.x + threadIdx.x;
    float v = 0.f;
    for (int e = i; e < N_EDGES; e += gridDim.x * blockDim.x) v += ea[e];
    #pragma unroll
    for (int off = 32; off >= 1; off >>= 1) v += __shfl_xor(v, off);
    if ((threadIdx.x & 63) == 0) atomicAdd(&scalars[25], v);
}

// ---------------- we_dot per head + ea_mean ----------------
__global__ void k_wedot(const float* __restrict__ We1, const float* __restrict__ ae1,
                        const float* __restrict__ We2, const float* __restrict__ ae2,
                        float* scalars) {
    int t = threadIdx.x;
    if (t < NH1) {
        float s = 0.f;
        for (int c = 0; c < NC1; c++) s += We1[t * NC1 + c] * ae1[t * NC1 + c];
        scalars[1 + t] = s;
    } else if (t < NH1 + NH2) {
        int h = t - NH1;
        float s = 0.f;
        for (int c = 0; c < NC2; c++) s += We2[h * NC2 + c] * ae2[h * NC2 + c];
        scalars[17 + h] = s;
    } else if (t == 63) {
        scalars[0] = scalars[25] / (float)N_EDGES;   // ea_mean
    }
}

// ---------------- in-degree histogram ----------------
__global__ void k_hist(const int* __restrict__ ei, int* counts) {
    int e = blockIdx.x * blockDim.x + threadIdx.x;
    if (e < N_EDGES) atomicAdd(&counts[ei[N_EDGES + e]], 1);
}

// ---------------- exclusive scan (1 block, wave-scan based) ----------------
__global__ __launch_bounds__(1024) void k_scan(const int* __restrict__ counts,
                                               int* rowptr, int* cursor) {
    __shared__ int wsum[16];
    __shared__ int carry_s;
    int t = threadIdx.x;
    int lane = t & 63, w = t >> 6;
    if (t == 0) carry_s = 0;
    __syncthreads();
    for (int base = 0; base < N_NODES; base += 1024) {
        int i = base + t;
        int v = (i < N_NODES) ? counts[i] : 0;
        int incl = v;
        #pragma unroll
        for (int off = 1; off < 64; off <<= 1) {
            int u = __shfl_up(incl, off);
            if (lane >= off) incl += u;
        }
        if (lane == 63) wsum[w] = incl;
        __syncthreads();
        int woff = 0;
        for (int k = 0; k < w; k++) woff += wsum[k];
        int carry = carry_s;
        int excl = carry + woff + incl - v;
        if (i < N_NODES) { rowptr[i] = excl; cursor[i] = excl; }
        __syncthreads();
        if (t == 1023) carry_s = carry + woff + incl;
        __syncthreads();
    }
    if (t == 0) rowptr[N_NODES] = carry_s;
}

// ---------------- scatter edges (+self loops) into CSR ----------------
__global__ void k_scatter(const int* __restrict__ ei, const float* __restrict__ ea,
                          const float* __restrict__ scalars, int* cursor,
                          int* csr_src, float* csr_ea) {
    int i = blockIdx.x * blockDim.x + threadIdx.x;
    if (i < N_EDGES) {
        int s = ei[i], d = ei[N_EDGES + i];
        int pos = atomicAdd(&cursor[d], 1);
        csr_src[pos] = s;
        csr_ea[pos] = ea[i];
    } else if (i < N_TOT) {
        int n = i - N_EDGES;
        int pos = atomicAdd(&cursor[n], 1);
        csr_src[pos] = n;
        csr_ea[pos] = scalars[0];
    }
}

// ---------------- convert x -> (xh, xl) bf16 split, padded [MPAD][KP] ----------------
__global__ void k_cvt_x(const float* __restrict__ x, uint16_t* __restrict__ xh,
                        uint16_t* __restrict__ xl) {
    int idx = blockIdx.x * 256 + threadIdx.x;     // row*28 + kw
    if (idx >= MPAD * 28) return;
    int row = idx / 28, kw = idx - row * 28;
    int k0 = kw * 8;
    uint16_t hv[8], lv[8];
    #pragma unroll
    for (int j = 0; j < 8; j++) {
        int k = k0 + j;
        float v = (row < N_NODES && k < IN_F) ? x[(size_t)row * IN_F + k] : 0.f;
        float hf;
        hv[j] = f2bf(v, &hf);
        float lo = v - hf;
        float lf;
        lv[j] = f2bf(lo, &lf);
    }
    *(uint4*)(xh + (size_t)row * KP + k0) = *(const uint4*)hv;
    *(uint4*)(xl + (size_t)row * KP + k0) = *(const uint4*)lv;
}

// ---------------- convert W1 -> (WhT, WlT) bf16 split transposed [F1][KP] ----------------
__global__ void k_cvt_w(const float* __restrict__ W1, uint16_t* __restrict__ wht,
                        uint16_t* __restrict__ wlt) {
    int idx = blockIdx.x * 256 + threadIdx.x;     // col*28 + kw
    if (idx >= F1 * 28) return;
    int col = idx / 28, kw = idx - col * 28;
    int k0 = kw * 8;
    uint16_t hv[8], lv[8];
    #pragma unroll
    for (int j = 0; j < 8; j++) {
        int k = k0 + j;
        float v = (k < IN_F) ? W1[(size_t)k * F1 + col] : 0.f;
        float hf;
        hv[j] = f2bf(v, &hf);
        float lo = v - hf;
        float lf;
        lv[j] = f2bf(lo, &lf);
    }
    *(uint4*)(wht + (size_t)col * KP + k0) = *(const uint4*)hv;
    *(uint4*)(wlt + (size_t)col * KP + k0) = *(const uint4*)lv;
}

// ---------------- GEMM1 via MFMA: xl1 = x @ W1, bf16 hi/lo split (3 terms) ----------------
// Output written as bf16.
__global__ __launch_bounds__(256) void k_gemm1_mfma(const uint16_t* __restrict__ xh,
        const uint16_t* __restrict__ xl, const uint16_t* __restrict__ wht,
        const uint16_t* __restrict__ wlt, uint16_t* __restrict__ xl1b) {
    __shared__ uint16_t lds[4 * 8 * 64 * 8];   // Ah, Al, Bh, Bl ; 32 KiB
    const int t = threadIdx.x;
    const int l = t & 63, w = t >> 6;
    const int wm = w >> 1, wn = w & 1;
    const int m0 = blockIdx.x * 128;
    const int n0 = blockIdx.y * 128;
    const int lr = l & 15, lk = l >> 4;

    uint16_t* ldsAh = lds;
    uint16_t* ldsAl = lds + 8 * 64 * 8;
    uint16_t* ldsBh = lds + 2 * 8 * 64 * 8;
    uint16_t* ldsBl = lds + 3 * 8 * 64 * 8;

    f32x4 acc[4][4];
    #pragma unroll
    for (int i = 0; i < 4; i++)
        #pragma unroll
        for (int j = 0; j < 4; j++)
            acc[i][j] = (f32x4){0.f, 0.f, 0.f, 0.f};

    for (int ks = 0; ks < 7; ks++) {
        const int kb = ks * 32 + lk * 8;
        #pragma unroll
        for (int ii = 0; ii < 2; ii++) {
            const int f = 2 * w + ii;
            const uint16_t* sAh = xh  + (size_t)(m0 + f * 16 + lr) * KP + kb;
            const uint16_t* sAl = xl  + (size_t)(m0 + f * 16 + lr) * KP + kb;
            const uint16_t* sBh = wht + (size_t)(n0 + f * 16 + lr) * KP + kb;
            const uint16_t* sBl = wlt + (size_t)(n0 + f * 16 + lr) * KP + kb;
            GLL16(sAh, ldsAh + f * 512);
            GLL16(sAl, ldsAl + f * 512);
            GLL16(sBh, ldsBh + f * 512);
            GLL16(sBl, ldsBl + f * 512);
        }
        __syncthreads();
        bf16x8 ah[4], al[4];
        #pragma unroll
        for (int i = 0; i < 4; i++) {
            const int f = wm * 4 + i;
            ah[i] = *(const bf16x8*)(ldsAh + (f * 64 + l) * 8);
            al[i] = *(const bf16x8*)(ldsAl + (f * 64 + l) * 8);
        }
        #pragma unroll
        for (int j = 0; j < 4; j++) {
            const int g = wn * 4 + j;
            bf16x8 bh = *(const bf16x8*)(ldsBh + (g * 64 + l) * 8);
            bf16x8 bl = *(const bf16x8*)(ldsBl + (g * 64 + l) * 8);
            #pragma unroll
            for (int i = 0; i < 4; i++) {
                acc[i][j] = __builtin_amdgcn_mfma_f32_16x16x32_bf16(ah[i], bh, acc[i][j], 0, 0, 0);
                acc[i][j] = __builtin_amdgcn_mfma_f32_16x16x32_bf16(ah[i], bl, acc[i][j], 0, 0, 0);
                acc[i][j] = __builtin_amdgcn_mfma_f32_16x16x32_bf16(al[i], bh, acc[i][j], 0, 0, 0);
            }
        }
        __syncthreads();
    }
    // C write (bf16): row = (lane>>4)*4 + r, col = lane&15 within each frag
    #pragma unroll
    for (int i = 0; i < 4; i++) {
        const int gm_base = m0 + wm * 64 + i * 16 + lk * 4;
        #pragma unroll
        for (int r = 0; r < 4; r++) {
            const int gm = gm_base + r;
            if (gm < N_NODES) {
                #pragma unroll
                for (int j = 0; j < 4; j++) {
                    const int gn = n0 + wn * 64 + j * 16 + lr;
                    xl1b[(size_t)gm * F1 + gn] = f2bf1(acc[i][j][r]);
                }
            }
        }
    }
}

// ---------------- alpha_src1/alpha_dst1 (bf16 xl1) ----------------
__global__ void k_alphas1(const uint16_t* __restrict__ xl1b, const float* __restrict__ a_src,
                          const float* __restrict__ a_dst,
                          float* __restrict__ asrc, float* __restrict__ adst) {
    int idx = blockIdx.x * blockDim.x + threadIdx.x;   // n*16 + h
    if (idx >= N_NODES * NH1) return;
    int h = idx & 15;
    const uint4* xp = (const uint4*)(xl1b + (size_t)idx * 16);
    uint4 u0 = xp[0], u1 = xp[1];
    uint32_t us[8] = {u0.x, u0.y, u0.z, u0.w, u1.x, u1.y, u1.z, u1.w};
    float as = 0.f, ad = 0.f;
    #pragma unroll
    for (int q = 0; q < 8; q++) {
        float lo, hi;
        bf2f2(us[q], &lo, &hi);
        as += lo * a_src[h * 16 + 2 * q] + hi * a_src[h * 16 + 2 * q + 1];
        ad += lo * a_dst[h * 16 + 2 * q] + hi * a_dst[h * 16 + 2 * q + 1];
    }
    asrc[idx] = as;
    adst[idx] = ad;
}

// ---------------- aggregation layer 1 (wave per node, single pass, bf16 gather) ----------------
__global__ __launch_bounds__(256) void k_agg1(const int* __restrict__ rowptr,
        const int* __restrict__ csr_src, const float* __restrict__ csr_ea,
        const uint16_t* __restrict__ xl1b, const float* __restrict__ asrc,
        const float* __restrict__ adst, const float* __restrict__ scalars,
        const float* __restrict__ b1, uint16_t* __restrict__ h1b) {
    int node = blockIdx.x * 4 + (threadIdx.x >> 6);
    int lane = threadIdx.x & 63;
    int eg = lane >> 4, h = lane & 15;
    int r0 = rowptr[node], r1 = rowptr[node + 1];
    float ad = adst[node * 16 + h];
    float wd = scalars[1 + h];
    float den = 0.f;
    float acc[16];
    #pragma unroll
    for (int c = 0; c < 16; c++) acc[c] = 0.f;
    for (int j = r0 + eg; j < r1; j += 4) {
        int s = csr_src[j];
        float a = lrelu(asrc[s * 16 + h] + ad + csr_ea[j] * wd);
        float wgt = __expf(a);           // no max-shift: logits bounded, fp32 safe
        den += wgt;
        const uint4* xp = (const uint4*)(xl1b + (size_t)s * F1 + h * 16);
        uint4 u0 = xp[0], u1 = xp[1];
        float lo, hi;
        bf2f2(u0.x, &lo, &hi); acc[0] += wgt * lo;  acc[1] += wgt * hi;
        bf2f2(u0.y, &lo, &hi); acc[2] += wgt * lo;  acc[3] += wgt * hi;
        bf2f2(u0.z, &lo, &hi); acc[4] += wgt * lo;  acc[5] += wgt * hi;
        bf2f2(u0.w, &lo, &hi); acc[6] += wgt * lo;  acc[7] += wgt * hi;
        bf2f2(u1.x, &lo, &hi); acc[8] += wgt * lo;  acc[9] += wgt * hi;
        bf2f2(u1.y, &lo, &hi); acc[10] += wgt * lo; acc[11] += wgt * hi;
        bf2f2(u1.z, &lo, &hi); acc[12] += wgt * lo; acc[13] += wgt * hi;
        bf2f2(u1.w, &lo, &hi); acc[14] += wgt * lo; acc[15] += wgt * hi;
    }
    den += __shfl_xor(den, 16);
    den += __shfl_xor(den, 32);
    float inv = 1.f / (den + 1e-16f);
    #pragma unroll
    for (int c = 0; c < 16; c++) {
        acc[c] += __shfl_xor(acc[c], 16);
        acc[c] += __shfl_xor(acc[c], 32);
    }
    if (eg == 0) {
        uint32_t pk[8];
        #pragma unroll
        for (int q = 0; q < 8; q++) {
            float v0 = acc[2 * q] * inv + b1[h * 16 + 2 * q];
            float v1 = acc[2 * q + 1] * inv + b1[h * 16 + 2 * q + 1];
            v0 = v0 > 0.f ? v0 : expm1f(v0);   // ELU
            v1 = v1 > 0.f ? v1 : expm1f(v1);
            pk[q] = (uint32_t)f2bf1(v0) | ((uint32_t)f2bf1(v1) << 16);
        }
        uint4* op = (uint4*)(h1b + (size_t)node * F1 + h * 16);
        op[0] = make_uint4(pk[0], pk[1], pk[2], pk[3]);
        op[1] = make_uint4(pk[4], pk[5], pk[6], pk[7]);
    }
}

// ---------------- GEMM2: xl2 = h1 @ W2  (50000x256 @ 256x24), bf16 h1 ----------------
__global__ __launch_bounds__(256) void k_gemm2(const uint16_t* __restrict__ h1b,
                                               const float* __restrict__ W2,
                                               float* __restrict__ xl2) {
    __shared__ float W2t[F2][260];
    int t = threadIdx.x;
    for (int i = t; i < 256 * F2; i += 256) {
        int k = i / F2, c = i - k * F2;
        W2t[c][k] = W2[i];
    }
    __syncthreads();
    int idx = blockIdx.x * 256 + t;
    if (idx >= N_NODES * F2) return;
    int n = idx / F2, col = idx - n * F2;
    const uint4* hp = (const uint4*)(h1b + (size_t)n * F1);
    float acc = 0.f;
    #pragma unroll 4
    for (int q = 0; q < 32; q++) {
        uint4 u = hp[q];
        const float4* wp = (const float4*)(&W2t[col][q * 8]);
        float4 w0 = wp[0], w1 = wp[1];
        float lo, hi;
        bf2f2(u.x, &lo, &hi); acc += lo * w0.x + hi * w0.y;
        bf2f2(u.y, &lo, &hi); acc += lo * w0.z + hi * w0.w;
        bf2f2(u.z, &lo, &hi); acc += lo * w1.x + hi * w1.y;
        bf2f2(u.w, &lo, &hi); acc += lo * w1.z + hi * w1.w;
    }
    xl2[idx] = acc;
}

// ---------------- alpha_src2/alpha_dst2 ----------------
__global__ void k_alphas2(const float* __restrict__ xl2, const float* __restrict__ a_src,
                          const float* __restrict__ a_dst,
                          float* __restrict__ asrc, float* __restrict__ adst) {
    int idx = blockIdx.x * blockDim.x + threadIdx.x;   // n*8 + h
    if (idx >= N_NODES * NH2) return;
    int h = idx & 7;
    float x0 = xl2[idx * 3 + 0], x1 = xl2[idx * 3 + 1], x2 = xl2[idx * 3 + 2];
    asrc[idx] = x0 * a_src[h * 3 + 0] + x1 * a_src[h * 3 + 1] + x2 * a_src[h * 3 + 2];
    adst[idx] = x0 * a_dst[h * 3 + 0] + x1 * a_dst[h * 3 + 1] + x2 * a_dst[h * 3 + 2];
}

// ---------------- aggregation layer 2 (wave per node, single pass) ----------------
__global__ __launch_bounds__(256) void k_agg2(const int* __restrict__ rowptr,
        const int* __restrict__ csr_src, const float* __restrict__ csr_ea,
        const float* __restrict__ xl2, const float* __restrict__ asrc,
        const float* __restrict__ adst, const float* __restrict__ scalars,
        const float* __restrict__ b2, float* __restrict__ out) {
    int node = blockIdx.x * 4 + (threadIdx.x >> 6);
    int lane = threadIdx.x & 63;
    int eg = lane >> 3, h = lane & 7;
    int r0 = rowptr[node], r1 = rowptr[node + 1];
    float ad = adst[node * 8 + h];
    float wd = scalars[17 + h];
    float den = 0.f, a0 = 0.f, a1 = 0.f, a2 = 0.f;
    for (int j = r0 + eg; j < r1; j += 8) {
        int s = csr_src[j];
        float a = lrelu(asrc[s * 8 + h] + ad + csr_ea[j] * wd);
        float wgt = __expf(a);
        den += wgt;
        const float* xp = xl2 + (size_t)s * F2 + h * 3;
        a0 += wgt * xp[0];
        a1 += wgt * xp[1];
        a2 += wgt * xp[2];
    }
    den += __shfl_xor(den, 8); den += __shfl_xor(den, 16); den += __shfl_xor(den, 32);
    float inv = 1.f / (den + 1e-16f);
    a0 += __shfl_xor(a0, 8); a0 += __shfl_xor(a0, 16); a0 += __shfl_xor(a0, 32);
    a1 += __shfl_xor(a1, 8); a1 += __shfl_xor(a1, 16); a1 += __shfl_xor(a1, 32);
    a2 += __shfl_xor(a2, 8); a2 += __shfl_xor(a2, 16); a2 += __shfl_xor(a2, 32);
    a0 *= inv; a1 *= inv; a2 *= inv;
    a0 += __shfl_xor(a0, 1); a0 += __shfl_xor(a0, 2); a0 += __shfl_xor(a0, 4);
    a1 += __shfl_xor(a1, 1); a1 += __shfl_xor(a1, 2); a1 += __shfl_xor(a1, 4);
    a2 += __shfl_xor(a2, 1); a2 += __shfl_xor(a2, 2); a2 += __shfl_xor(a2, 4);
    if (lane == 0) {
        float v0 = a0 * 0.125f + b2[0];
        float v1 = a1 * 0.125f + b2[1];
        float v2 = a2 * 0.125f + b2[2];
        out[node * 3 + 0] = v0 > 0.f ? v0 : expm1f(v0);
        out[node * 3 + 1] = v1 > 0.f ? v1 : expm1f(v1);
        out[node * 3 + 2] = v2 > 0.f ? v2 : expm1f(v2);
    }
}

extern "C" void kernel_launch(void* const* d_in, const int* in_sizes, int n_in,
                              void* d_out, int out_size, void* d_ws, size_t ws_size,
                              hipStream_t stream) {
    const float* x       = (const float*)d_in[0];
    const int*   ei      = (const int*)d_in[1];
    const float* ea      = (const float*)d_in[2];
    const float* W1      = (const float*)d_in[3];
    const float* We1     = (const float*)d_in[4];
    const float* a_src1  = (const float*)d_in[5];
    const float* a_dst1  = (const float*)d_in[6];
    const float* a_edge1 = (const float*)d_in[7];
    const float* b1      = (const float*)d_in[8];
    const float* W2      = (const float*)d_in[9];
    const float* We2     = (const float*)d_in[10];
    const float* a_src2  = (const float*)d_in[11];
    const float* a_dst2  = (const float*)d_in[12];
    const float* a_edge2 = (const float*)d_in[13];
    const float* b2      = (const float*)d_in[14];
    float* out = (float*)d_out;

    char* ws = (char*)d_ws;
    size_t off = 0;
    auto alloc = [&](size_t nbytes) -> void* {
        void* p = ws + off;
        off = (off + nbytes + 255) & ~(size_t)255;
        return p;
    };
    uint16_t* xl1b = (uint16_t*)alloc((size_t)N_NODES * F1 * 2);
    uint16_t* h1b  = (uint16_t*)alloc((size_t)N_NODES * F1 * 2);
    float* asrc1   = (float*)alloc((size_t)N_NODES * NH1 * 4);
    float* adst1   = (float*)alloc((size_t)N_NODES * NH1 * 4);
    float* xl2     = (float*)alloc((size_t)N_NODES * F2 * 4);
    float* asrc2   = (float*)alloc((size_t)N_NODES * NH2 * 4);
    float* adst2   = (float*)alloc((size_t)N_NODES * NH2 * 4);
    int*   counts  = (int*)alloc((size_t)N_NODES * 4);
    int*   rowptr  = (int*)alloc((size_t)(N_NODES + 1) * 4);
    int*   cursor  = (int*)alloc((size_t)N_NODES * 4);
    int*   csr_src = (int*)alloc((size_t)N_TOT * 4);
    float* csr_ea  = (float*)alloc((size_t)N_TOT * 4);
    float* scalars = (float*)alloc(128);
    uint16_t* wht  = (uint16_t*)alloc((size_t)F1 * KP * 2);
    uint16_t* wlt  = (uint16_t*)alloc((size_t)F1 * KP * 2);
    uint16_t* xh   = (uint16_t*)alloc((size_t)MPAD * KP * 2);
    uint16_t* xlo  = (uint16_t*)alloc((size_t)MPAD * KP * 2);

    hipLaunchKernelGGL(k_init, dim3((N_NODES + 255) / 256), dim3(256), 0, stream,
                       counts, scalars);
    hipLaunchKernelGGL(k_easum, dim3(256), dim3(256), 0, stream, ea, scalars);
    hipLaunchKernelGGL(k_wedot, dim3(1), dim3(64), 0, stream,
                       We1, a_edge1, We2, a_edge2, scalars);
    hipLaunchKernelGGL(k_hist, dim3((N_EDGES + 255) / 256), dim3(256), 0, stream,
                       ei, counts);
    hipLaunchKernelGGL(k_scan, dim3(1), dim3(1024), 0, stream, counts, rowptr, cursor);
    hipLaunchKernelGGL(k_scatter, dim3((N_TOT + 255) / 256), dim3(256), 0, stream,
                       ei, ea, scalars, cursor, csr_src, csr_ea);
    hipLaunchKernelGGL(k_cvt_x, dim3((MPAD * 28 + 255) / 256), dim3(256), 0, stream,
                       x, xh, xlo);
    hipLaunchKernelGGL(k_cvt_w, dim3((F1 * 28 + 255) / 256), dim3(256), 0, stream,
                       W1, wht, wlt);
    hipLaunchKernelGGL(k_gemm1_mfma, dim3(MPAD / 128, 2), dim3(256), 0, stream,
                       xh, xlo, wht, wlt, xl1b);
    hipLaunchKernelGGL(k_alphas1, dim3((N_NODES * NH1 + 255) / 256), dim3(256), 0, stream,
                       xl1b, a_src1, a_dst1, asrc1, adst1);
    hipLaunchKernelGGL(k_agg1, dim3(N_NODES / 4), dim3(256), 0, stream,
                       rowptr, csr_src, csr_ea, xl1b, asrc1, adst1, scalars, b1, h1b);
    hipLaunchKernelGGL(k_gemm2, dim3((N_NODES * F2 + 255) / 256), dim3(256), 0, stream,
                       h1b, W2, xl2);
    hipLaunchKernelGGL(k_alphas2, dim3((N_NODES * NH2 + 255) / 256), dim3(256), 0, stream,
                       xl2, a_src2, a_dst2, asrc2, adst2);
    hipLaunchKernelGGL(k_agg2, dim3(N_NODES / 4), dim3(256), 0, stream,
                       rowptr, csr_src, csr_ea, xl2, asrc2, adst2, scalars, b2, out);
}